// Round 4
// baseline (397.184 us; speedup 1.0000x reference)
//
#include <hip/hip_runtime.h>
#include <math.h>

// Problem constants
#define BB 32
#define NN 1024
#define DD 768
#define KK 512
#define MM (BB * NN)  // 32768 token rows

typedef _Float16 half8 __attribute__((ext_vector_type(8)));
typedef _Float16 half4 __attribute__((ext_vector_type(4)));
typedef float floatx4 __attribute__((ext_vector_type(4)));

// LDS-only barrier: waits ds ops, leaves global loads/stores in flight.
// Legal when no cross-thread communication goes through global memory.
__device__ __forceinline__ void bar_lds() {
    asm volatile("s_waitcnt lgkmcnt(0)" ::: "memory");
    __builtin_amdgcn_s_barrier();
}

// ---------------------------------------------------------------------------
// Codebook prep (merged): fp32->fp16 cast + csq[k] = sum_d cb[k][d]^2
// ---------------------------------------------------------------------------
__global__ __launch_bounds__(256) void prep_codebook(const float* __restrict__ cb,
                                                     _Float16* __restrict__ Cbh,
                                                     float* __restrict__ csq) {
    int k = blockIdx.x;
    const float* row = cb + (size_t)k * DD;
    _Float16* orow = Cbh + (size_t)k * DD;
    float s = 0.f;
    for (int d = threadIdx.x; d < DD; d += 256) {
        float v = row[d];
        s += v * v;
        orow[d] = (_Float16)v;
    }
    #pragma unroll
    for (int off = 32; off > 0; off >>= 1) s += __shfl_down(s, off);
    __shared__ float sm[4];
    int lane = threadIdx.x & 63, wid = threadIdx.x >> 6;
    if (lane == 0) sm[wid] = s;
    __syncthreads();
    if (threadIdx.x == 0) csq[k] = sm[0] + sm[1] + sm[2] + sm[3];
}

// ---------------------------------------------------------------------------
// FUSED v6: logits (MFMA fp16) + softmax + St write + Xt write.
// Key change vs v5 (common-mistake #7): the 768 KB codebook is L2-resident —
// DROP the Cs LDS staging + lds-dma entirely; bf fragments are 16B-contiguous
// row segments of Cbh loaded DIRECT from global (1-iter register prefetch).
// Only Xs (8 KB, dbuf, XOR-swizzled, proven 0-conflict) stays in LDS, so the
// loop barrier is lgkm-only raw s_barrier: NO vmcnt drain anywhere -> global
// loads/stores pipeline freely across iterations.
// Xt [b][d][n] is written from the af fragment registers (waves 0-3, 2B
// stores in 32B segments) -> no LDS gather, no bank conflicts.
// ---------------------------------------------------------------------------
__global__ __launch_bounds__(512, 4) void fused_logits_softmax(
    const float* __restrict__ X,        // [M, D] fp32
    const _Float16* __restrict__ Cbh,   // [K, D] fp16
    const float* __restrict__ csq,      // [K]
    _Float16* __restrict__ St,          // [B, K, N] fp16
    _Float16* __restrict__ Xt)          // [B, D, N] fp16
{
    __shared__ _Float16 Xs[2][64][32];    // 8 KB double-buffered token chunk
    __shared__ float redbuf[8][64];       // per-wave softmax partials
    __shared__ float gred[64];            // reduced per-token value

    const int t = threadIdx.x;
    const int w = t >> 6;
    const int lane = t & 63;
    const int l15 = lane & 15;
    const int quad = lane >> 4;
    const int wk = w * 64;              // this wave's k slab
    const int gm0 = blockIdx.x * 64;    // global token base
    const int b = gm0 >> 10;
    const int n0 = gm0 & 1023;

    // swizzled 16B-unit column for Xs fragment reads
    const int qs = (quad ^ ((l15 >> 1) & 3)) * 8;

    float cs[4];
    #pragma unroll
    for (int ki = 0; ki < 4; ki++) cs[ki] = csq[wk + ki * 16 + l15];

    floatx4 acc[4][4] = {};

    // --- X staging (t<256): row cr, swizzled source col-chunk cq ---
    const int cr = t >> 2;
    const int cq = (t & 3) ^ ((t >> 3) & 3);
    const float* xsrc = X + (size_t)(gm0 + cr) * DD + cq * 8;

    // --- bf direct-global base: row (wk + ki*16 + l15), col chunk quad*8 ---
    const _Float16* cbp = Cbh + (size_t)(wk + l15) * DD + quad * 8;

    // --- Xt store base (waves 0-3): d-rows quad*8+j, n = n0 + w*16 + l15 ---
    _Float16* xtp = Xt + ((size_t)b * DD + quad * 8) * NN + n0 + (w & 3) * 16 + l15;

    float4 xa, xb;
    if (t < 256) { xa = *(const float4*)xsrc; xb = *(const float4*)(xsrc + 4); }

    // ---- prologue: stage chunk 0, prefetch X chunk 1, preload bf chunk 0 ----
    if (t < 256) {
        half8 h;
        h[0] = (_Float16)xa.x; h[1] = (_Float16)xa.y; h[2] = (_Float16)xa.z; h[3] = (_Float16)xa.w;
        h[4] = (_Float16)xb.x; h[5] = (_Float16)xb.y; h[6] = (_Float16)xb.z; h[7] = (_Float16)xb.w;
        *(half8*)&Xs[0][cr][(t & 3) * 8] = h;
        xa = *(const float4*)(xsrc + 32);
        xb = *(const float4*)(xsrc + 36);
    }
    half8 bfc[4], bfn[4];
    #pragma unroll
    for (int ki = 0; ki < 4; ki++)
        bfc[ki] = *(const half8*)(cbp + (size_t)(ki * 16) * DD);
    bar_lds();

    for (int it = 0; it < 24; ++it) {
        const int cur = it & 1;
        if (it < 23) {
            // stage chunk it+1 (data prefetched 2 iters ago)
            if (t < 256) {
                half8 h;
                h[0] = (_Float16)xa.x; h[1] = (_Float16)xa.y; h[2] = (_Float16)xa.z; h[3] = (_Float16)xa.w;
                h[4] = (_Float16)xb.x; h[5] = (_Float16)xb.y; h[6] = (_Float16)xb.z; h[7] = (_Float16)xb.w;
                *(half8*)&Xs[cur ^ 1][cr][(t & 3) * 8] = h;
                if (it < 22) {
                    xa = *(const float4*)(xsrc + (it + 2) * 32);
                    xb = *(const float4*)(xsrc + (it + 2) * 32 + 4);
                }
            }
            // prefetch next bf chunk (global, wave-private, floats across barrier)
            #pragma unroll
            for (int ki = 0; ki < 4; ki++)
                bfn[ki] = *(const half8*)(cbp + (size_t)(ki * 16) * DD + (it + 1) * 32);
        }
        // af fragments from swizzled Xs (proven conflict-free)
        half8 af[4];
        #pragma unroll
        for (int mi = 0; mi < 4; mi++)
            af[mi] = *(half8*)((_Float16*)Xs[cur] + (mi * 16 + l15) * 32 + qs);
        // MFMA
        #pragma unroll
        for (int mi = 0; mi < 4; mi++)
            #pragma unroll
            for (int ki = 0; ki < 4; ki++)
                acc[mi][ki] = __builtin_amdgcn_mfma_f32_16x16x32_f16(af[mi], bfc[ki], acc[mi][ki], 0, 0, 0);
        // Xt write from af registers: wave w<4 stores n-rows of token group mi=w
        if (w < 4) {
            #pragma unroll
            for (int mi = 0; mi < 4; mi++)
                if (mi == w) {
                    #pragma unroll
                    for (int j = 0; j < 8; j++)
                        xtp[(size_t)(it * 32 + j) * NN] = af[mi][j];
                }
        }
        if (it < 23) {
            bar_lds();
            #pragma unroll
            for (int ki = 0; ki < 4; ki++) bfc[ki] = bfn[ki];
        }
    }

    // ---- softmax over k=512 ----
    // logit = 2*acc - cs;  k = wk + ki*16 + l15, token = mi*16 + quad*4 + r
    float pmax[4][4];
    #pragma unroll
    for (int mi = 0; mi < 4; mi++)
        #pragma unroll
        for (int r = 0; r < 4; r++) {
            float m = -1e30f;
            #pragma unroll
            for (int ki = 0; ki < 4; ki++)
                m = fmaxf(m, 2.f * acc[mi][ki][r] - cs[ki]);
            pmax[mi][r] = m;
        }
    #pragma unroll
    for (int off = 1; off < 16; off <<= 1)
        #pragma unroll
        for (int mi = 0; mi < 4; mi++)
            #pragma unroll
            for (int r = 0; r < 4; r++)
                pmax[mi][r] = fmaxf(pmax[mi][r], __shfl_xor(pmax[mi][r], off));
    if (l15 == 0) {
        #pragma unroll
        for (int mi = 0; mi < 4; mi++)
            #pragma unroll
            for (int r = 0; r < 4; r++)
                redbuf[w][mi * 16 + quad * 4 + r] = pmax[mi][r];
    }
    bar_lds();
    if (t < 64) {
        float g = redbuf[0][t];
        #pragma unroll
        for (int wv = 1; wv < 8; wv++) g = fmaxf(g, redbuf[wv][t]);
        gred[t] = g;
    }
    bar_lds();
    float gmax[4][4];
    #pragma unroll
    for (int mi = 0; mi < 4; mi++)
        #pragma unroll
        for (int r = 0; r < 4; r++)
            gmax[mi][r] = gred[mi * 16 + quad * 4 + r];   // broadcast read
    bar_lds();   // gred/redbuf reuse below

    float psum[4][4] = {};
    #pragma unroll
    for (int mi = 0; mi < 4; mi++)
        #pragma unroll
        for (int ki = 0; ki < 4; ki++) {
            floatx4 e;
            #pragma unroll
            for (int r = 0; r < 4; r++) {
                e[r] = __expf(2.f * acc[mi][ki][r] - cs[ki] - gmax[mi][r]);
                psum[mi][r] += e[r];
            }
            acc[mi][ki] = e;
        }
    #pragma unroll
    for (int off = 1; off < 16; off <<= 1)
        #pragma unroll
        for (int mi = 0; mi < 4; mi++)
            #pragma unroll
            for (int r = 0; r < 4; r++)
                psum[mi][r] += __shfl_xor(psum[mi][r], off);
    if (l15 == 0) {
        #pragma unroll
        for (int mi = 0; mi < 4; mi++)
            #pragma unroll
            for (int r = 0; r < 4; r++)
                redbuf[w][mi * 16 + quad * 4 + r] = psum[mi][r];
    }
    bar_lds();
    if (t < 64) {
        float s = redbuf[0][t];
        #pragma unroll
        for (int wv = 1; wv < 8; wv++) s += redbuf[wv][t];
        gred[t] = 1.f / s;
    }
    bar_lds();
    float ginv[4][4];
    #pragma unroll
    for (int mi = 0; mi < 4; mi++)
        #pragma unroll
        for (int r = 0; r < 4; r++)
            ginv[mi][r] = gred[mi * 16 + quad * 4 + r];

    // scale + transposed store: St[b][k][n]
    #pragma unroll
    for (int mi = 0; mi < 4; mi++)
        #pragma unroll
        for (int ki = 0; ki < 4; ki++) {
            half4 s4;
            #pragma unroll
            for (int r = 0; r < 4; r++)
                s4[r] = (_Float16)(acc[mi][ki][r] * ginv[mi][r]);
            int k = wk + ki * 16 + l15;
            *(half4*)&St[((size_t)b * KK + k) * NN + n0 + mi * 16 + quad * 4] = s4;
        }
}

// ---------------------------------------------------------------------------
// GEMM2 v5: out[b][k][d] = sum_n St[b][k][n] * Xt[b][d][n]
// LDS-free, barrier-free (common-mistake #7): both operand fragments are
// 16B-contiguous row segments of L2/L3-resident St/Xt -> load DIRECT from
// global into double-buffered registers. Pure per-wave dataflow; the
// compiler software-pipelines vmcnt; occupancy + 16 independent acc chains
// hide the cache latency.
// ---------------------------------------------------------------------------
__global__ __launch_bounds__(256, 4) void gemm2_mfma(const _Float16* __restrict__ St,
                                                     const _Float16* __restrict__ Xt,
                                                     float* __restrict__ out) {
    const int d0 = blockIdx.x * 128;
    const int k0 = blockIdx.y * 128;
    const int b = blockIdx.z;
    const int t = threadIdx.x;
    const int wave = t >> 6;
    const int lane = t & 63;
    const int wm = (wave >> 1) * 64;
    const int wn = (wave & 1) * 64;
    const int l15 = lane & 15;
    const int quad = lane >> 4;

    floatx4 acc[4][4] = {};

    const _Float16* Ab = St + ((size_t)b * KK + k0 + wm + l15) * NN + quad * 8;
    const _Float16* Bb = Xt + ((size_t)b * DD + d0 + wn + l15) * NN + quad * 8;

    half8 a0[4], b0[4], a1[4], b1[4];
    #pragma unroll
    for (int i = 0; i < 4; i++) {
        a0[i] = *(const half8*)(Ab + (size_t)(i * 16) * NN);
        b0[i] = *(const half8*)(Bb + (size_t)(i * 16) * NN);
    }

    for (int n0 = 0; n0 < NN; n0 += 64) {
        #pragma unroll
        for (int i = 0; i < 4; i++) {
            a1[i] = *(const half8*)(Ab + (size_t)(i * 16) * NN + n0 + 32);
            b1[i] = *(const half8*)(Bb + (size_t)(i * 16) * NN + n0 + 32);
        }
        #pragma unroll
        for (int mi = 0; mi < 4; mi++)
            #pragma unroll
            for (int ni = 0; ni < 4; ni++)
                acc[mi][ni] = __builtin_amdgcn_mfma_f32_16x16x32_f16(a0[mi], b0[ni], acc[mi][ni], 0, 0, 0);
        if (n0 + 64 < NN) {
            #pragma unroll
            for (int i = 0; i < 4; i++) {
                a0[i] = *(const half8*)(Ab + (size_t)(i * 16) * NN + n0 + 64);
                b0[i] = *(const half8*)(Bb + (size_t)(i * 16) * NN + n0 + 64);
            }
        }
        #pragma unroll
        for (int mi = 0; mi < 4; mi++)
            #pragma unroll
            for (int ni = 0; ni < 4; ni++)
                acc[mi][ni] = __builtin_amdgcn_mfma_f32_16x16x32_f16(a1[mi], b1[ni], acc[mi][ni], 0, 0, 0);
    }

    #pragma unroll
    for (int ni = 0; ni < 4; ni++) {
        #pragma unroll
        for (int mi = 0; mi < 4; mi++) {
            int k = k0 + wm + mi * 16 + quad * 4;
            int d = d0 + wn + ni * 16 + l15;
            float* op = out + ((size_t)b * KK + k) * DD + d;
            floatx4 a = acc[mi][ni];
            op[0 * DD] = a[0];
            op[1 * DD] = a[1];
            op[2 * DD] = a[2];
            op[3 * DD] = a[3];
        }
    }
}

// ---------------------------------------------------------------------------
extern "C" void kernel_launch(void* const* d_in, const int* in_sizes, int n_in,
                              void* d_out, int out_size, void* d_ws, size_t ws_size,
                              hipStream_t stream) {
    const float* x  = (const float*)d_in[0];   // [B,N,D] fp32
    const float* cb = (const float*)d_in[1];   // [K,D] fp32
    float* out = (float*)d_out;                // [B,K,D] fp32

    char* ws = (char*)d_ws;
    float*    csq = (float*)ws;                                   // 4 KB
    _Float16* Cbh = (_Float16*)(ws + 4096);                       // 768 KB
    _Float16* Xt  = (_Float16*)(ws + 4096 + 786432);              // 48 MB [b][d][n]
    _Float16* St  = (_Float16*)(ws + 4096 + 786432 + 50331648);   // 32 MB [b][k][n]

    // codebook prep (merged cast + csq)
    prep_codebook<<<KK, 256, 0, stream>>>(cb, Cbh, csq);

    // fused logits + softmax -> St (fp16 [b][k][n]) AND X transpose -> Xt
    fused_logits_softmax<<<MM / 64, 512, 0, stream>>>(x, Cbh, csq, St, Xt);

    // aggregate
    gemm2_mfma<<<dim3(DD / 128, KK / 128, BB), 256, 0, stream>>>(St, Xt, out);
}

// Round 5
// 257.049 us; speedup vs baseline: 1.5452x; 1.5452x over previous
//
#include <hip/hip_runtime.h>
#include <math.h>

// Problem constants
#define BB 32
#define NN 1024
#define DD 768
#define KK 512
#define MM (BB * NN)  // 32768 token rows

typedef _Float16 half8 __attribute__((ext_vector_type(8)));
typedef _Float16 half4 __attribute__((ext_vector_type(4)));
typedef float floatx4 __attribute__((ext_vector_type(4)));

// async global(16B) -> LDS, per-lane dest = uniform base + lane*16
__device__ __forceinline__ void load_lds16(const void* g, void* l) {
    __builtin_amdgcn_global_load_lds(
        (const __attribute__((address_space(1))) unsigned int*)g,
        (__attribute__((address_space(3))) unsigned int*)l, 16, 0, 0);
}

// ---------------------------------------------------------------------------
// Codebook prep (merged): fp32->fp16 cast + csq[k] = sum_d cb[k][d]^2
// ---------------------------------------------------------------------------
__global__ __launch_bounds__(256) void prep_codebook(const float* __restrict__ cb,
                                                     _Float16* __restrict__ Cbh,
                                                     float* __restrict__ csq) {
    int k = blockIdx.x;
    const float* row = cb + (size_t)k * DD;
    _Float16* orow = Cbh + (size_t)k * DD;
    float s = 0.f;
    for (int d = threadIdx.x; d < DD; d += 256) {
        float v = row[d];
        s += v * v;
        orow[d] = (_Float16)v;
    }
    #pragma unroll
    for (int off = 32; off > 0; off >>= 1) s += __shfl_down(s, off);
    __shared__ float sm[4];
    int lane = threadIdx.x & 63, wid = threadIdx.x >> 6;
    if (lane == 0) sm[wid] = s;
    __syncthreads();
    if (threadIdx.x == 0) csq[k] = sm[0] + sm[1] + sm[2] + sm[3];
}

// ---------------------------------------------------------------------------
// FUSED v7: logits (MFMA fp16) + softmax + St write + Xt write.
// Structure = R3's v5 (measured 85.5 us): dbuf LDS, one __syncthreads per
// K-chunk, XOR swizzle (16B unit ^= (row>>1)&3), Cs via lds-dma (linear dest
// + pre-swizzled global source), X reg-roundtrip fp32->fp16.
// ONE change vs v5: Xt [b][d][n] is written from the af fragment REGISTERS
// (waves 0-3, statically-indexed mi==w), replacing the v5 LDS column gather
// that caused 5.5M bank-conflict cycles (~9 us).
// ---------------------------------------------------------------------------
__global__ __launch_bounds__(512, 4) void fused_logits_softmax(
    const float* __restrict__ X,        // [M, D] fp32
    const _Float16* __restrict__ Cbh,   // [K, D] fp16
    const float* __restrict__ csq,      // [K]
    _Float16* __restrict__ St,          // [B, K, N] fp16
    _Float16* __restrict__ Xt)          // [B, D, N] fp16
{
    __shared__ _Float16 Cs[2][512][32];   // 64 KB double-buffered codebook chunk
    __shared__ _Float16 Xs[2][64][32];    // 8 KB double-buffered token chunk
    __shared__ float redbuf[8][64];       // per-wave softmax partials
    __shared__ float gred[64];            // reduced per-token value

    const int t = threadIdx.x;
    const int w = t >> 6;
    const int lane = t & 63;
    const int l15 = lane & 15;
    const int quad = lane >> 4;
    const int wk = w * 64;              // this wave's k slab
    const int gm0 = blockIdx.x * 64;    // global token base
    const int b = gm0 >> 10;
    const int n0 = gm0 & 1023;

    // swizzled 16B-unit column for fragment reads (row swz bits = (l15>>1)&3)
    const int qs = (quad ^ ((l15 >> 1) & 3)) * 8;

    float cs[4];
    #pragma unroll
    for (int ki = 0; ki < 4; ki++) cs[ki] = csq[wk + ki * 16 + l15];

    floatx4 acc[4][4] = {};

    // --- staging roles ---
    // Cs: all 512 threads x 4 units; unit u=c*512+t -> row=c*128+(t>>2), phys q=t&3
    //     source col-chunk = q ^ swz(row) = (t&3) ^ ((t>>3)&3)
    const int cr = t >> 2;
    const int cq = (t & 3) ^ ((t >> 3) & 3);
    // Xs: threads t<256, 16B fp32 x2 -> half8 at phys unit (t&3), row cr
    const float* xsrc = X + (size_t)(gm0 + cr) * DD + cq * 8;

    // Xt store base (waves 0-3): token n = n0 + w*16 + l15, d-rows quad*8+j
    _Float16* xtp = Xt + ((size_t)b * DD + quad * 8) * NN + n0 + (w & 3) * 16 + l15;

    float4 xa, xb;
    if (t < 256) { xa = *(const float4*)xsrc; xb = *(const float4*)(xsrc + 4); }

    // ---- prologue: stage chunk 0, prefetch X chunk 1 ----
    #pragma unroll
    for (int c = 0; c < 4; c++)
        load_lds16(Cbh + (size_t)(c * 128 + cr) * DD + cq * 8,
                   (_Float16*)Cs[0] + (c * 512 + t) * 8);
    if (t < 256) {
        half8 h;
        h[0] = (_Float16)xa.x; h[1] = (_Float16)xa.y; h[2] = (_Float16)xa.z; h[3] = (_Float16)xa.w;
        h[4] = (_Float16)xb.x; h[5] = (_Float16)xb.y; h[6] = (_Float16)xb.z; h[7] = (_Float16)xb.w;
        *(half8*)&Xs[0][cr][(t & 3) * 8] = h;
        xa = *(const float4*)(xsrc + 32);
        xb = *(const float4*)(xsrc + 36);
    }
    __syncthreads();

    int cur = 0;
    for (int it = 0; it < 24; ++it) {
        const int d0 = it * 32;
        // stage chunk it+1 into the other buffer (latency hides under compute)
        if (it + 1 < 24) {
            const int d0n = d0 + 32;
            #pragma unroll
            for (int c = 0; c < 4; c++)
                load_lds16(Cbh + (size_t)(c * 128 + cr) * DD + d0n + cq * 8,
                           (_Float16*)Cs[cur ^ 1] + (c * 512 + t) * 8);
            if (t < 256) {
                half8 h;
                h[0] = (_Float16)xa.x; h[1] = (_Float16)xa.y; h[2] = (_Float16)xa.z; h[3] = (_Float16)xa.w;
                h[4] = (_Float16)xb.x; h[5] = (_Float16)xb.y; h[6] = (_Float16)xb.z; h[7] = (_Float16)xb.w;
                *(half8*)&Xs[cur ^ 1][cr][(t & 3) * 8] = h;
                if (it + 2 < 24) {
                    xa = *(const float4*)(xsrc + (it + 2) * 32);
                    xb = *(const float4*)(xsrc + (it + 2) * 32 + 4);
                }
            }
        }
        // fragments
        half8 af[4], bf[4];
        #pragma unroll
        for (int mi = 0; mi < 4; mi++)
            af[mi] = *(half8*)((_Float16*)Xs[cur] + (mi * 16 + l15) * 32 + qs);
        #pragma unroll
        for (int ki = 0; ki < 4; ki++)
            bf[ki] = *(half8*)((_Float16*)Cs[cur] + (wk + ki * 16 + l15) * 32 + qs);
        // Xt write from af registers (waves 0-3; static index via mi==w):
        // af[mi][j] = X[gm0 + mi*16 + l15][d0 + quad*8 + j]
        if (w < 4) {
            #pragma unroll
            for (int mi = 0; mi < 4; mi++)
                if (mi == w) {
                    #pragma unroll
                    for (int j = 0; j < 8; j++)
                        xtp[(size_t)(d0 + j) * NN] = af[mi][j];
                }
        }
        // MFMA
        #pragma unroll
        for (int mi = 0; mi < 4; mi++)
            #pragma unroll
            for (int ki = 0; ki < 4; ki++)
                acc[mi][ki] = __builtin_amdgcn_mfma_f32_16x16x32_f16(af[mi], bf[ki], acc[mi][ki], 0, 0, 0);
        if (it + 1 < 24) { __syncthreads(); cur ^= 1; }
    }

    // ---- softmax over k=512 ----
    // logit = 2*acc - cs;  k = wk + ki*16 + l15, token = mi*16 + quad*4 + r
    float pmax[4][4];
    #pragma unroll
    for (int mi = 0; mi < 4; mi++)
        #pragma unroll
        for (int r = 0; r < 4; r++) {
            float m = -1e30f;
            #pragma unroll
            for (int ki = 0; ki < 4; ki++)
                m = fmaxf(m, 2.f * acc[mi][ki][r] - cs[ki]);
            pmax[mi][r] = m;
        }
    #pragma unroll
    for (int off = 1; off < 16; off <<= 1)
        #pragma unroll
        for (int mi = 0; mi < 4; mi++)
            #pragma unroll
            for (int r = 0; r < 4; r++)
                pmax[mi][r] = fmaxf(pmax[mi][r], __shfl_xor(pmax[mi][r], off));
    if (l15 == 0) {
        #pragma unroll
        for (int mi = 0; mi < 4; mi++)
            #pragma unroll
            for (int r = 0; r < 4; r++)
                redbuf[w][mi * 16 + quad * 4 + r] = pmax[mi][r];
    }
    __syncthreads();
    if (t < 64) {
        float g = redbuf[0][t];
        #pragma unroll
        for (int wv = 1; wv < 8; wv++) g = fmaxf(g, redbuf[wv][t]);
        gred[t] = g;
    }
    __syncthreads();
    float gmax[4][4];
    #pragma unroll
    for (int mi = 0; mi < 4; mi++)
        #pragma unroll
        for (int r = 0; r < 4; r++)
            gmax[mi][r] = gred[mi * 16 + quad * 4 + r];   // broadcast read
    __syncthreads();   // redbuf/gred reuse below

    float psum[4][4] = {};
    #pragma unroll
    for (int mi = 0; mi < 4; mi++)
        #pragma unroll
        for (int ki = 0; ki < 4; ki++) {
            floatx4 e;
            #pragma unroll
            for (int r = 0; r < 4; r++) {
                e[r] = __expf(2.f * acc[mi][ki][r] - cs[ki] - gmax[mi][r]);
                psum[mi][r] += e[r];
            }
            acc[mi][ki] = e;
        }
    #pragma unroll
    for (int off = 1; off < 16; off <<= 1)
        #pragma unroll
        for (int mi = 0; mi < 4; mi++)
            #pragma unroll
            for (int r = 0; r < 4; r++)
                psum[mi][r] += __shfl_xor(psum[mi][r], off);
    if (l15 == 0) {
        #pragma unroll
        for (int mi = 0; mi < 4; mi++)
            #pragma unroll
            for (int r = 0; r < 4; r++)
                redbuf[w][mi * 16 + quad * 4 + r] = psum[mi][r];
    }
    __syncthreads();
    if (t < 64) {
        float s = redbuf[0][t];
        #pragma unroll
        for (int wv = 1; wv < 8; wv++) s += redbuf[wv][t];
        gred[t] = 1.f / s;
    }
    __syncthreads();
    float ginv[4][4];
    #pragma unroll
    for (int mi = 0; mi < 4; mi++)
        #pragma unroll
        for (int r = 0; r < 4; r++)
            ginv[mi][r] = gred[mi * 16 + quad * 4 + r];

    // scale + transposed store: St[b][k][n]
    #pragma unroll
    for (int mi = 0; mi < 4; mi++)
        #pragma unroll
        for (int ki = 0; ki < 4; ki++) {
            half4 s4;
            #pragma unroll
            for (int r = 0; r < 4; r++)
                s4[r] = (_Float16)(acc[mi][ki][r] * ginv[mi][r]);
            int k = wk + ki * 16 + l15;
            *(half4*)&St[((size_t)b * KK + k) * NN + n0 + mi * 16 + quad * 4] = s4;
        }
}

// ---------------------------------------------------------------------------
// GEMM2 v7: out[b][k][d] = sum_n St[b][k][n] * Xt[b][d][n]
// Proven R3 body (128x128 tile, BK=32, dbuf LDS via lds-dma, XOR swizzle,
// one __syncthreads per K-step) + NEW: 1-D grid with b-major linearization
// and bijective XCD swizzle (T1). 768 blocks = 32 b x (4 k-blk x 6 d-blk);
// xcd = lin&7, wg = xcd*96 + (lin>>3) -> each XCD owns 4 consecutive b's,
// whose 2.5 MB St+Xt working set fits its 4 MB L2 (St reused x6, Xt x4).
// R4 measured the no-reuse cost: 469 MB FETCH, 170 us. Ideal ~80 MB.
// ---------------------------------------------------------------------------
__global__ __launch_bounds__(256, 4) void gemm2_mfma(const _Float16* __restrict__ St,
                                                     const _Float16* __restrict__ Xt,
                                                     float* __restrict__ out) {
    __shared__ _Float16 As[2][128][32];  // 16 KB
    __shared__ _Float16 Bs[2][128][32];  // 16 KB

    // bijective XCD swizzle over 768 blocks (768 % 8 == 0)
    const int lin = blockIdx.x;
    const int wg = (lin & 7) * 96 + (lin >> 3);
    const int b = wg / 24;
    const int rr = wg % 24;
    const int k0 = (rr / 6) * 128;
    const int d0 = (rr % 6) * 128;

    const int t = threadIdx.x;
    const int wave = t >> 6;
    const int lane = t & 63;
    const int wm = (wave >> 1) * 64;
    const int wn = (wave & 1) * 64;
    const int l15 = lane & 15;
    const int quad = lane >> 4;
    const int qs = (quad ^ ((l15 >> 1) & 3)) * 8;

    const int cr = t >> 2;                       // row within 64-row group
    const int cq = (t & 3) ^ ((t >> 3) & 3);     // swizzled source col-chunk

    floatx4 acc[4][4] = {};

    const _Float16* Abase = St + ((size_t)b * KK + k0) * NN;
    const _Float16* Bbase = Xt + ((size_t)b * DD + d0) * NN;

    // prologue: stage chunk 0
    #pragma unroll
    for (int c = 0; c < 2; c++) {
        load_lds16(Abase + (size_t)(c * 64 + cr) * NN + cq * 8,
                   (_Float16*)As[0] + (c * 256 + t) * 8);
        load_lds16(Bbase + (size_t)(c * 64 + cr) * NN + cq * 8,
                   (_Float16*)Bs[0] + (c * 256 + t) * 8);
    }
    __syncthreads();

    int cur = 0;
    for (int it = 0; it < 32; ++it) {
        if (it + 1 < 32) {
            const int n0 = (it + 1) * 32;
            #pragma unroll
            for (int c = 0; c < 2; c++) {
                load_lds16(Abase + (size_t)(c * 64 + cr) * NN + n0 + cq * 8,
                           (_Float16*)As[cur ^ 1] + (c * 256 + t) * 8);
                load_lds16(Bbase + (size_t)(c * 64 + cr) * NN + n0 + cq * 8,
                           (_Float16*)Bs[cur ^ 1] + (c * 256 + t) * 8);
            }
        }
        half8 af[4], bf[4];
        #pragma unroll
        for (int i = 0; i < 4; i++) af[i] = *(half8*)&As[cur][wm + i * 16 + l15][qs];
        #pragma unroll
        for (int i = 0; i < 4; i++) bf[i] = *(half8*)&Bs[cur][wn + i * 16 + l15][qs];
        #pragma unroll
        for (int mi = 0; mi < 4; mi++)
            #pragma unroll
            for (int ni = 0; ni < 4; ni++)
                acc[mi][ni] = __builtin_amdgcn_mfma_f32_16x16x32_f16(af[mi], bf[ni], acc[mi][ni], 0, 0, 0);
        if (it + 1 < 32) { __syncthreads(); cur ^= 1; }
    }

    #pragma unroll
    for (int ni = 0; ni < 4; ni++) {
        #pragma unroll
        for (int mi = 0; mi < 4; mi++) {
            int k = k0 + wm + mi * 16 + quad * 4;
            int d = d0 + wn + ni * 16 + l15;
            float* op = out + ((size_t)b * KK + k) * DD + d;
            floatx4 a = acc[mi][ni];
            op[0 * DD] = a[0];
            op[1 * DD] = a[1];
            op[2 * DD] = a[2];
            op[3 * DD] = a[3];
        }
    }
}

// ---------------------------------------------------------------------------
extern "C" void kernel_launch(void* const* d_in, const int* in_sizes, int n_in,
                              void* d_out, int out_size, void* d_ws, size_t ws_size,
                              hipStream_t stream) {
    const float* x  = (const float*)d_in[0];   // [B,N,D] fp32
    const float* cb = (const float*)d_in[1];   // [K,D] fp32
    float* out = (float*)d_out;                // [B,K,D] fp32

    char* ws = (char*)d_ws;
    float*    csq = (float*)ws;                                   // 4 KB
    _Float16* Cbh = (_Float16*)(ws + 4096);                       // 768 KB
    _Float16* Xt  = (_Float16*)(ws + 4096 + 786432);              // 48 MB [b][d][n]
    _Float16* St  = (_Float16*)(ws + 4096 + 786432 + 50331648);   // 32 MB [b][k][n]

    // codebook prep (merged cast + csq)
    prep_codebook<<<KK, 256, 0, stream>>>(cb, Cbh, csq);

    // fused logits + softmax -> St (fp16 [b][k][n]) AND X transpose -> Xt
    fused_logits_softmax<<<MM / 64, 512, 0, stream>>>(x, Cbh, csq, St, Xt);

    // aggregate (b-major + XCD swizzle)
    gemm2_mfma<<<768, 256, 0, stream>>>(St, Xt, out);
}

// Round 7
// 255.217 us; speedup vs baseline: 1.5563x; 1.0072x over previous
//
#include <hip/hip_runtime.h>
#include <math.h>

// Problem constants
#define BB 32
#define NN 1024
#define DD 768
#define KK 512
#define MM (BB * NN)  // 32768 token rows

typedef _Float16 half8 __attribute__((ext_vector_type(8)));
typedef _Float16 half4 __attribute__((ext_vector_type(4)));
typedef float floatx4 __attribute__((ext_vector_type(4)));

// async global(16B) -> LDS, per-lane dest = uniform base + lane*16
__device__ __forceinline__ void load_lds16(const void* g, void* l) {
    __builtin_amdgcn_global_load_lds(
        (const __attribute__((address_space(1))) unsigned int*)g,
        (__attribute__((address_space(3))) unsigned int*)l, 16, 0, 0);
}

// ---------------------------------------------------------------------------
// Codebook prep (merged): fp32->fp16 cast + csq[k] = sum_d cb[k][d]^2
// ---------------------------------------------------------------------------
__global__ __launch_bounds__(256) void prep_codebook(const float* __restrict__ cb,
                                                     _Float16* __restrict__ Cbh,
                                                     float* __restrict__ csq) {
    int k = blockIdx.x;
    const float* row = cb + (size_t)k * DD;
    _Float16* orow = Cbh + (size_t)k * DD;
    float s = 0.f;
    for (int d = threadIdx.x; d < DD; d += 256) {
        float v = row[d];
        s += v * v;
        orow[d] = (_Float16)v;
    }
    #pragma unroll
    for (int off = 32; off > 0; off >>= 1) s += __shfl_down(s, off);
    __shared__ float sm[4];
    int lane = threadIdx.x & 63, wid = threadIdx.x >> 6;
    if (lane == 0) sm[wid] = s;
    __syncthreads();
    if (threadIdx.x == 0) csq[k] = sm[0] + sm[1] + sm[2] + sm[3];
}

// ---------------------------------------------------------------------------
// FUSED v8: logits (MFMA fp16) + softmax + St write + Xt write.
// Structure = R3's v5 (measured 85.5 us): dbuf LDS, one __syncthreads per
// K-chunk, XOR swizzle (16B unit ^= (row>>1)&3), Cs via lds-dma (linear dest
// + pre-swizzled global source), X reg-roundtrip fp32->fp16, Xt written via
// LDS gather from Xs + coalesced half4 stores.
// ONE change vs R3: the gather's THREAD MAP is d = t&31, i = t>>5 (was
// d = t>>4, i = t&15). Bank(n,d) = 16(n&1) + 4((d>>3)^((n>>1)&3)) + ((d&7)>>1);
// the new map spans all 4 d-octets and all 4 (d&7)>>1 values per wave ->
// 16 distinct banks, d-pairs (2k,2k+1) share a 4B word (broadcast) ->
// <=2-way (free, m136). R3's map left ~16-way: 14 cyc x 393K instrs = the
// measured 5.5M conflict cycles. R5's register-store alternative was WORSE
// (scatter stores drained by __syncthreads each iter: 100 us).
// ---------------------------------------------------------------------------
__global__ __launch_bounds__(512, 4) void fused_logits_softmax(
    const float* __restrict__ X,        // [M, D] fp32
    const _Float16* __restrict__ Cbh,   // [K, D] fp16
    const float* __restrict__ csq,      // [K]
    _Float16* __restrict__ St,          // [B, K, N] fp16
    _Float16* __restrict__ Xt)          // [B, D, N] fp16
{
    __shared__ _Float16 Cs[2][512][32];   // 64 KB double-buffered codebook chunk
    __shared__ _Float16 Xs[2][64][32];    // 8 KB double-buffered token chunk
    __shared__ float redbuf[8][64];       // per-wave softmax partials
    __shared__ float gred[64];            // reduced per-token value

    const int t = threadIdx.x;
    const int w = t >> 6;
    const int lane = t & 63;
    const int l15 = lane & 15;
    const int quad = lane >> 4;
    const int wk = w * 64;              // this wave's k slab
    const int gm0 = blockIdx.x * 64;    // global token base
    const int b = gm0 >> 10;
    const int n0 = gm0 & 1023;

    // swizzled 16B-unit column for fragment reads (row swz bits = (l15>>1)&3)
    const int qs = (quad ^ ((l15 >> 1) & 3)) * 8;

    float cs[4];
    #pragma unroll
    for (int ki = 0; ki < 4; ki++) cs[ki] = csq[wk + ki * 16 + l15];

    floatx4 acc[4][4] = {};

    // --- staging roles ---
    // Cs: all 512 threads x 4 units; unit u=c*512+t -> row=c*128+(t>>2), phys q=t&3
    //     source col-chunk = q ^ swz(row) = (t&3) ^ ((t>>3)&3)
    const int cr = t >> 2;
    const int cq = (t & 3) ^ ((t >> 3) & 3);
    // Xs: threads t<256, 16B fp32 x2 -> half8 at phys unit (t&3), row cr
    const float* xsrc = X + (size_t)(gm0 + cr) * DD + cq * 8;

    // Xt gather map (conflict-free): d = t&31, n-quad base = (t>>5)*4
    const int tdr = t & 31;             // d within chunk, 0..31
    const int tn4 = (t >> 5) * 4;       // n base, 0..60

    float4 xa, xb;
    if (t < 256) { xa = *(const float4*)xsrc; xb = *(const float4*)(xsrc + 4); }

    // ---- prologue: stage chunk 0, prefetch X chunk 1 ----
    #pragma unroll
    for (int c = 0; c < 4; c++)
        load_lds16(Cbh + (size_t)(c * 128 + cr) * DD + cq * 8,
                   (_Float16*)Cs[0] + (c * 512 + t) * 8);
    if (t < 256) {
        half8 h;
        h[0] = (_Float16)xa.x; h[1] = (_Float16)xa.y; h[2] = (_Float16)xa.z; h[3] = (_Float16)xa.w;
        h[4] = (_Float16)xb.x; h[5] = (_Float16)xb.y; h[6] = (_Float16)xb.z; h[7] = (_Float16)xb.w;
        *(half8*)&Xs[0][cr][(t & 3) * 8] = h;
        xa = *(const float4*)(xsrc + 32);
        xb = *(const float4*)(xsrc + 36);
    }
    __syncthreads();

    int cur = 0;
    for (int it = 0; it < 24; ++it) {
        const int d0 = it * 32;
        // stage chunk it+1 into the other buffer (latency hides under compute)
        if (it + 1 < 24) {
            const int d0n = d0 + 32;
            #pragma unroll
            for (int c = 0; c < 4; c++)
                load_lds16(Cbh + (size_t)(c * 128 + cr) * DD + d0n + cq * 8,
                           (_Float16*)Cs[cur ^ 1] + (c * 512 + t) * 8);
            if (t < 256) {
                half8 h;
                h[0] = (_Float16)xa.x; h[1] = (_Float16)xa.y; h[2] = (_Float16)xa.z; h[3] = (_Float16)xa.w;
                h[4] = (_Float16)xb.x; h[5] = (_Float16)xb.y; h[6] = (_Float16)xb.z; h[7] = (_Float16)xb.w;
                *(half8*)&Xs[cur ^ 1][cr][(t & 3) * 8] = h;
                if (it + 2 < 24) {
                    xa = *(const float4*)(xsrc + (it + 2) * 32);
                    xb = *(const float4*)(xsrc + (it + 2) * 32 + 4);
                }
            }
        }
        // Xt write-back of current chunk: LDS gather (<=2-way banks) + half4 store
        {
            half4 xo;
            #pragma unroll
            for (int j = 0; j < 4; j++) {
                int n = tn4 + j;
                xo[j] = *((const _Float16*)Xs[cur] + n * 32 +
                          (((tdr >> 3) ^ ((n >> 1) & 3)) << 3) + (tdr & 7));
            }
            *(half4*)&Xt[((size_t)b * DD + d0 + tdr) * NN + n0 + tn4] = xo;
        }
        // fragments
        half8 af[4], bf[4];
        #pragma unroll
        for (int mi = 0; mi < 4; mi++)
            af[mi] = *(half8*)((_Float16*)Xs[cur] + (mi * 16 + l15) * 32 + qs);
        #pragma unroll
        for (int ki = 0; ki < 4; ki++)
            bf[ki] = *(half8*)((_Float16*)Cs[cur] + (wk + ki * 16 + l15) * 32 + qs);
        // MFMA
        #pragma unroll
        for (int mi = 0; mi < 4; mi++)
            #pragma unroll
            for (int ki = 0; ki < 4; ki++)
                acc[mi][ki] = __builtin_amdgcn_mfma_f32_16x16x32_f16(af[mi], bf[ki], acc[mi][ki], 0, 0, 0);
        if (it + 1 < 24) { __syncthreads(); cur ^= 1; }
    }

    // ---- softmax over k=512 ----
    // logit = 2*acc - cs;  k = wk + ki*16 + l15, token = mi*16 + quad*4 + r
    float pmax[4][4];
    #pragma unroll
    for (int mi = 0; mi < 4; mi++)
        #pragma unroll
        for (int r = 0; r < 4; r++) {
            float m = -1e30f;
            #pragma unroll
            for (int ki = 0; ki < 4; ki++)
                m = fmaxf(m, 2.f * acc[mi][ki][r] - cs[ki]);
            pmax[mi][r] = m;
        }
    #pragma unroll
    for (int off = 1; off < 16; off <<= 1)
        #pragma unroll
        for (int mi = 0; mi < 4; mi++)
            #pragma unroll
            for (int r = 0; r < 4; r++)
                pmax[mi][r] = fmaxf(pmax[mi][r], __shfl_xor(pmax[mi][r], off));
    if (l15 == 0) {
        #pragma unroll
        for (int mi = 0; mi < 4; mi++)
            #pragma unroll
            for (int r = 0; r < 4; r++)
                redbuf[w][mi * 16 + quad * 4 + r] = pmax[mi][r];
    }
    __syncthreads();
    if (t < 64) {
        float g = redbuf[0][t];
        #pragma unroll
        for (int wv = 1; wv < 8; wv++) g = fmaxf(g, redbuf[wv][t]);
        gred[t] = g;
    }
    __syncthreads();
    float gmax[4][4];
    #pragma unroll
    for (int mi = 0; mi < 4; mi++)
        #pragma unroll
        for (int r = 0; r < 4; r++)
            gmax[mi][r] = gred[mi * 16 + quad * 4 + r];   // broadcast read
    __syncthreads();   // redbuf/gred reuse below

    float psum[4][4] = {};
    #pragma unroll
    for (int mi = 0; mi < 4; mi++)
        #pragma unroll
        for (int ki = 0; ki < 4; ki++) {
            floatx4 e;
            #pragma unroll
            for (int r = 0; r < 4; r++) {
                e[r] = __expf(2.f * acc[mi][ki][r] - cs[ki] - gmax[mi][r]);
                psum[mi][r] += e[r];
            }
            acc[mi][ki] = e;
        }
    #pragma unroll
    for (int off = 1; off < 16; off <<= 1)
        #pragma unroll
        for (int mi = 0; mi < 4; mi++)
            #pragma unroll
            for (int r = 0; r < 4; r++)
                psum[mi][r] += __shfl_xor(psum[mi][r], off);
    if (l15 == 0) {
        #pragma unroll
        for (int mi = 0; mi < 4; mi++)
            #pragma unroll
            for (int r = 0; r < 4; r++)
                redbuf[w][mi * 16 + quad * 4 + r] = psum[mi][r];
    }
    __syncthreads();
    if (t < 64) {
        float s = redbuf[0][t];
        #pragma unroll
        for (int wv = 1; wv < 8; wv++) s += redbuf[wv][t];
        gred[t] = 1.f / s;
    }
    __syncthreads();
    float ginv[4][4];
    #pragma unroll
    for (int mi = 0; mi < 4; mi++)
        #pragma unroll
        for (int r = 0; r < 4; r++)
            ginv[mi][r] = gred[mi * 16 + quad * 4 + r];

    // scale + transposed store: St[b][k][n]
    #pragma unroll
    for (int mi = 0; mi < 4; mi++)
        #pragma unroll
        for (int ki = 0; ki < 4; ki++) {
            half4 s4;
            #pragma unroll
            for (int r = 0; r < 4; r++)
                s4[r] = (_Float16)(acc[mi][ki][r] * ginv[mi][r]);
            int k = wk + ki * 16 + l15;
            *(half4*)&St[((size_t)b * KK + k) * NN + n0 + mi * 16 + quad * 4] = s4;
        }
}

// ---------------------------------------------------------------------------
// GEMM2 v7 (unchanged from R5): out[b][k][d] = sum_n St[b][k][n] * Xt[b][d][n]
// 128x128 tile, BK=32, dbuf LDS via lds-dma, XOR swizzle, one __syncthreads
// per K-step; 1-D grid, b-major linearization + bijective XCD swizzle so each
// XCD's L2 holds 4 b's 2.5 MB working set (St reused x6, Xt x4).
// R4 measured the no-reuse cost: 469 MB FETCH, 170 us; R5 left top-5 (<99 us).
// ---------------------------------------------------------------------------
__global__ __launch_bounds__(256, 4) void gemm2_mfma(const _Float16* __restrict__ St,
                                                     const _Float16* __restrict__ Xt,
                                                     float* __restrict__ out) {
    __shared__ _Float16 As[2][128][32];  // 16 KB
    __shared__ _Float16 Bs[2][128][32];  // 16 KB

    // bijective XCD swizzle over 768 blocks (768 % 8 == 0)
    const int lin = blockIdx.x;
    const int wg = (lin & 7) * 96 + (lin >> 3);
    const int b = wg / 24;
    const int rr = wg % 24;
    const int k0 = (rr / 6) * 128;
    const int d0 = (rr % 6) * 128;

    const int t = threadIdx.x;
    const int wave = t >> 6;
    const int lane = t & 63;
    const int wm = (wave >> 1) * 64;
    const int wn = (wave & 1) * 64;
    const int l15 = lane & 15;
    const int quad = lane >> 4;
    const int qs = (quad ^ ((l15 >> 1) & 3)) * 8;

    const int cr = t >> 2;                       // row within 64-row group
    const int cq = (t & 3) ^ ((t >> 3) & 3);     // swizzled source col-chunk

    floatx4 acc[4][4] = {};

    const _Float16* Abase = St + ((size_t)b * KK + k0) * NN;
    const _Float16* Bbase = Xt + ((size_t)b * DD + d0) * NN;

    // prologue: stage chunk 0
    #pragma unroll
    for (int c = 0; c < 2; c++) {
        load_lds16(Abase + (size_t)(c * 64 + cr) * NN + cq * 8,
                   (_Float16*)As[0] + (c * 256 + t) * 8);
        load_lds16(Bbase + (size_t)(c * 64 + cr) * NN + cq * 8,
                   (_Float16*)Bs[0] + (c * 256 + t) * 8);
    }
    __syncthreads();

    int cur = 0;
    for (int it = 0; it < 32; ++it) {
        if (it + 1 < 32) {
            const int n0 = (it + 1) * 32;
            #pragma unroll
            for (int c = 0; c < 2; c++) {
                load_lds16(Abase + (size_t)(c * 64 + cr) * NN + n0 + cq * 8,
                           (_Float16*)As[cur ^ 1] + (c * 256 + t) * 8);
                load_lds16(Bbase + (size_t)(c * 64 + cr) * NN + n0 + cq * 8,
                           (_Float16*)Bs[cur ^ 1] + (c * 256 + t) * 8);
            }
        }
        half8 af[4], bf[4];
        #pragma unroll
        for (int i = 0; i < 4; i++) af[i] = *(half8*)&As[cur][wm + i * 16 + l15][qs];
        #pragma unroll
        for (int i = 0; i < 4; i++) bf[i] = *(half8*)&Bs[cur][wn + i * 16 + l15][qs];
        #pragma unroll
        for (int mi = 0; mi < 4; mi++)
            #pragma unroll
            for (int ni = 0; ni < 4; ni++)
                acc[mi][ni] = __builtin_amdgcn_mfma_f32_16x16x32_f16(af[mi], bf[ni], acc[mi][ni], 0, 0, 0);
        if (it + 1 < 32) { __syncthreads(); cur ^= 1; }
    }

    #pragma unroll
    for (int ni = 0; ni < 4; ni++) {
        #pragma unroll
        for (int mi = 0; mi < 4; mi++) {
            int k = k0 + wm + mi * 16 + quad * 4;
            int d = d0 + wn + ni * 16 + l15;
            float* op = out + ((size_t)b * KK + k) * DD + d;
            floatx4 a = acc[mi][ni];
            op[0 * DD] = a[0];
            op[1 * DD] = a[1];
            op[2 * DD] = a[2];
            op[3 * DD] = a[3];
        }
    }
}

// ---------------------------------------------------------------------------
extern "C" void kernel_launch(void* const* d_in, const int* in_sizes, int n_in,
                              void* d_out, int out_size, void* d_ws, size_t ws_size,
                              hipStream_t stream) {
    const float* x  = (const float*)d_in[0];   // [B,N,D] fp32
    const float* cb = (const float*)d_in[1];   // [K,D] fp32
    float* out = (float*)d_out;                // [B,K,D] fp32

    char* ws = (char*)d_ws;
    float*    csq = (float*)ws;                                   // 4 KB
    _Float16* Cbh = (_Float16*)(ws + 4096);                       // 768 KB
    _Float16* Xt  = (_Float16*)(ws + 4096 + 786432);              // 48 MB [b][d][n]
    _Float16* St  = (_Float16*)(ws + 4096 + 786432 + 50331648);   // 32 MB [b][k][n]

    // codebook prep (merged cast + csq)
    prep_codebook<<<KK, 256, 0, stream>>>(cb, Cbh, csq);

    // fused logits + softmax -> St (fp16 [b][k][n]) AND X transpose -> Xt
    fused_logits_softmax<<<MM / 64, 512, 0, stream>>>(x, Cbh, csq, St, Xt);

    // aggregate (b-major + XCD swizzle)
    gemm2_mfma<<<768, 256, 0, stream>>>(St, Xt, out);
}

// Round 8
// 239.103 us; speedup vs baseline: 1.6611x; 1.0674x over previous
//
#include <hip/hip_runtime.h>
#include <math.h>

// Problem constants
#define BB 32
#define NN 1024
#define DD 768
#define KK 512
#define MM (BB * NN)  // 32768 token rows

typedef _Float16 half8 __attribute__((ext_vector_type(8)));
typedef _Float16 half4 __attribute__((ext_vector_type(4)));
typedef float floatx4 __attribute__((ext_vector_type(4)));

// async global(16B) -> LDS, per-lane dest = uniform base + lane*16
__device__ __forceinline__ void load_lds16(const void* g, void* l) {
    __builtin_amdgcn_global_load_lds(
        (const __attribute__((address_space(1))) unsigned int*)g,
        (__attribute__((address_space(3))) unsigned int*)l, 16, 0, 0);
}

// ---------------------------------------------------------------------------
// Codebook prep (merged): fp32->fp16 cast + csq[k] = sum_d cb[k][d]^2
// ---------------------------------------------------------------------------
__global__ __launch_bounds__(256) void prep_codebook(const float* __restrict__ cb,
                                                     _Float16* __restrict__ Cbh,
                                                     float* __restrict__ csq) {
    int k = blockIdx.x;
    const float* row = cb + (size_t)k * DD;
    _Float16* orow = Cbh + (size_t)k * DD;
    float s = 0.f;
    for (int d = threadIdx.x; d < DD; d += 256) {
        float v = row[d];
        s += v * v;
        orow[d] = (_Float16)v;
    }
    #pragma unroll
    for (int off = 32; off > 0; off >>= 1) s += __shfl_down(s, off);
    __shared__ float sm[4];
    int lane = threadIdx.x & 63, wid = threadIdx.x >> 6;
    if (lane == 0) sm[wid] = s;
    __syncthreads();
    if (threadIdx.x == 0) csq[k] = sm[0] + sm[1] + sm[2] + sm[3];
}

// ---------------------------------------------------------------------------
// FUSED v9: logits (MFMA fp16) + softmax + St write + Xt write.
// Body = R3's v5 (measured 85.5 us): dbuf LDS, XOR swizzle (16B unit ^=
// (row>>1)&3), Cs via lds-dma (linear dest + pre-swizzled source), X
// reg-roundtrip fp32->fp16, Xt gather map d = t>>4 / n4 = (t&15)*4
// (COALESCED stores: 4 rows x 128B per wave; its ~5.5M LDS conflict-cycles
// are hidden in this latency-bound kernel — R7 proved the "conflict-free"
// map's store scatter costs 15 us, conflicts cost ~0).
// NEW vs R3: K-loop barrier is raw s_barrier + COUNTED vmcnt (T4), draining
// ONLY the 4 lds-dma: the 2 X-prefetch HBM loads (consumed next iter) and
// the Xt store stay in flight. A "" memory clobber after the dma issue pins
// them oldest so vmcnt(3)/(1) is exact. lgkmcnt(0) still covers ds ops.
// (R2's counted-vmcnt failure bundled sched_barrier pins + staging remap;
// this is the isolated retry on the proven structure.)
// ---------------------------------------------------------------------------
__global__ __launch_bounds__(512, 4) void fused_logits_softmax(
    const float* __restrict__ X,        // [M, D] fp32
    const _Float16* __restrict__ Cbh,   // [K, D] fp16
    const float* __restrict__ csq,      // [K]
    _Float16* __restrict__ St,          // [B, K, N] fp16
    _Float16* __restrict__ Xt)          // [B, D, N] fp16
{
    __shared__ _Float16 Cs[2][512][32];   // 64 KB double-buffered codebook chunk
    __shared__ _Float16 Xs[2][64][32];    // 8 KB double-buffered token chunk
    __shared__ float redbuf[8][64];       // per-wave softmax partials
    __shared__ float gred[64];            // reduced per-token value

    const int t = threadIdx.x;
    const int w = t >> 6;
    const int lane = t & 63;
    const int l15 = lane & 15;
    const int quad = lane >> 4;
    const int wk = w * 64;              // this wave's k slab
    const int gm0 = blockIdx.x * 64;    // global token base
    const int b = gm0 >> 10;
    const int n0 = gm0 & 1023;

    // swizzled 16B-unit column for fragment reads (row swz bits = (l15>>1)&3)
    const int qs = (quad ^ ((l15 >> 1) & 3)) * 8;

    float cs[4];
    #pragma unroll
    for (int ki = 0; ki < 4; ki++) cs[ki] = csq[wk + ki * 16 + l15];

    floatx4 acc[4][4] = {};

    // --- staging roles ---
    // Cs: all 512 threads x 4 units; unit u=c*512+t -> row=c*128+(t>>2), phys q=t&3
    //     source col-chunk = q ^ swz(row) = (t&3) ^ ((t>>3)&3)
    const int cr = t >> 2;
    const int cq = (t & 3) ^ ((t >> 3) & 3);
    // Xs: threads t<256, 16B fp32 x2 -> half8 at phys unit (t&3), row cr
    const float* xsrc = X + (size_t)(gm0 + cr) * DD + cq * 8;

    // Xt gather map (R3, store-coalesced): d = t>>4, n base = (t&15)*4
    const int tdr = t >> 4;             // d within chunk, 0..31
    const int tn4 = (t & 15) * 4;       // n base, 0..60

    float4 xa, xb;
    if (t < 256) { xa = *(const float4*)xsrc; xb = *(const float4*)(xsrc + 4); }

    // ---- prologue: stage chunk 0, prefetch X chunk 1, full drain (once) ----
    #pragma unroll
    for (int c = 0; c < 4; c++)
        load_lds16(Cbh + (size_t)(c * 128 + cr) * DD + cq * 8,
                   (_Float16*)Cs[0] + (c * 512 + t) * 8);
    if (t < 256) {
        half8 h;
        h[0] = (_Float16)xa.x; h[1] = (_Float16)xa.y; h[2] = (_Float16)xa.z; h[3] = (_Float16)xa.w;
        h[4] = (_Float16)xb.x; h[5] = (_Float16)xb.y; h[6] = (_Float16)xb.z; h[7] = (_Float16)xb.w;
        *(half8*)&Xs[0][cr][(t & 3) * 8] = h;
        xa = *(const float4*)(xsrc + 32);
        xb = *(const float4*)(xsrc + 36);
    }
    __syncthreads();

    int cur = 0;
    for (int it = 0; it < 24; ++it) {
        const int d0 = it * 32;
        // stage chunk it+1 into the other buffer (latency hides under compute)
        if (it + 1 < 24) {
            const int d0n = d0 + 32;
            #pragma unroll
            for (int c = 0; c < 4; c++)
                load_lds16(Cbh + (size_t)(c * 128 + cr) * DD + d0n + cq * 8,
                           (_Float16*)Cs[cur ^ 1] + (c * 512 + t) * 8);
            // pin: the 4 lds-dma stay OLDEST in the vmcnt queue
            asm volatile("" ::: "memory");
            if (t < 256) {
                half8 h;
                h[0] = (_Float16)xa.x; h[1] = (_Float16)xa.y; h[2] = (_Float16)xa.z; h[3] = (_Float16)xa.w;
                h[4] = (_Float16)xb.x; h[5] = (_Float16)xb.y; h[6] = (_Float16)xb.z; h[7] = (_Float16)xb.w;
                *(half8*)&Xs[cur ^ 1][cr][(t & 3) * 8] = h;
                if (it + 2 < 24) {
                    xa = *(const float4*)(xsrc + (it + 2) * 32);
                    xb = *(const float4*)(xsrc + (it + 2) * 32 + 4);
                }
            }
        }
        // Xt write-back of current chunk: LDS gather + coalesced half4 store
        {
            half4 xo;
            #pragma unroll
            for (int j = 0; j < 4; j++) {
                int n = tn4 + j;
                xo[j] = *((const _Float16*)Xs[cur] + n * 32 +
                          (((tdr >> 3) ^ ((n >> 1) & 3)) << 3) + (tdr & 7));
            }
            *(half4*)&Xt[((size_t)b * DD + d0 + tdr) * NN + n0 + tn4] = xo;
        }
        // fragments
        half8 af[4], bf[4];
        #pragma unroll
        for (int mi = 0; mi < 4; mi++)
            af[mi] = *(half8*)((_Float16*)Xs[cur] + (mi * 16 + l15) * 32 + qs);
        #pragma unroll
        for (int ki = 0; ki < 4; ki++)
            bf[ki] = *(half8*)((_Float16*)Cs[cur] + (wk + ki * 16 + l15) * 32 + qs);
        // MFMA
        #pragma unroll
        for (int mi = 0; mi < 4; mi++)
            #pragma unroll
            for (int ki = 0; ki < 4; ki++)
                acc[mi][ki] = __builtin_amdgcn_mfma_f32_16x16x32_f16(af[mi], bf[ki], acc[mi][ki], 0, 0, 0);
        // counted barrier: drain ONLY the 4 lds-dma (oldest); leave the
        // X prefetch (w<4, if issued) + Xt store in flight across it
        if (it + 1 < 24) {
            if (it + 2 < 24 && w < 4)
                asm volatile("s_waitcnt vmcnt(3) lgkmcnt(0)" ::: "memory");
            else
                asm volatile("s_waitcnt vmcnt(1) lgkmcnt(0)" ::: "memory");
            __builtin_amdgcn_s_barrier();
            cur ^= 1;
        }
    }

    // ---- softmax over k=512 ----
    // logit = 2*acc - cs;  k = wk + ki*16 + l15, token = mi*16 + quad*4 + r
    float pmax[4][4];
    #pragma unroll
    for (int mi = 0; mi < 4; mi++)
        #pragma unroll
        for (int r = 0; r < 4; r++) {
            float m = -1e30f;
            #pragma unroll
            for (int ki = 0; ki < 4; ki++)
                m = fmaxf(m, 2.f * acc[mi][ki][r] - cs[ki]);
            pmax[mi][r] = m;
        }
    #pragma unroll
    for (int off = 1; off < 16; off <<= 1)
        #pragma unroll
        for (int mi = 0; mi < 4; mi++)
            #pragma unroll
            for (int r = 0; r < 4; r++)
                pmax[mi][r] = fmaxf(pmax[mi][r], __shfl_xor(pmax[mi][r], off));
    if (l15 == 0) {
        #pragma unroll
        for (int mi = 0; mi < 4; mi++)
            #pragma unroll
            for (int r = 0; r < 4; r++)
                redbuf[w][mi * 16 + quad * 4 + r] = pmax[mi][r];
    }
    __syncthreads();
    if (t < 64) {
        float g = redbuf[0][t];
        #pragma unroll
        for (int wv = 1; wv < 8; wv++) g = fmaxf(g, redbuf[wv][t]);
        gred[t] = g;
    }
    __syncthreads();
    float gmax[4][4];
    #pragma unroll
    for (int mi = 0; mi < 4; mi++)
        #pragma unroll
        for (int r = 0; r < 4; r++)
            gmax[mi][r] = gred[mi * 16 + quad * 4 + r];   // broadcast read
    __syncthreads();   // redbuf/gred reuse below

    float psum[4][4] = {};
    #pragma unroll
    for (int mi = 0; mi < 4; mi++)
        #pragma unroll
        for (int ki = 0; ki < 4; ki++) {
            floatx4 e;
            #pragma unroll
            for (int r = 0; r < 4; r++) {
                e[r] = __expf(2.f * acc[mi][ki][r] - cs[ki] - gmax[mi][r]);
                psum[mi][r] += e[r];
            }
            acc[mi][ki] = e;
        }
    #pragma unroll
    for (int off = 1; off < 16; off <<= 1)
        #pragma unroll
        for (int mi = 0; mi < 4; mi++)
            #pragma unroll
            for (int r = 0; r < 4; r++)
                psum[mi][r] += __shfl_xor(psum[mi][r], off);
    if (l15 == 0) {
        #pragma unroll
        for (int mi = 0; mi < 4; mi++)
            #pragma unroll
            for (int r = 0; r < 4; r++)
                redbuf[w][mi * 16 + quad * 4 + r] = psum[mi][r];
    }
    __syncthreads();
    if (t < 64) {
        float s = redbuf[0][t];
        #pragma unroll
        for (int wv = 1; wv < 8; wv++) s += redbuf[wv][t];
        gred[t] = 1.f / s;
    }
    __syncthreads();
    float ginv[4][4];
    #pragma unroll
    for (int mi = 0; mi < 4; mi++)
        #pragma unroll
        for (int r = 0; r < 4; r++)
            ginv[mi][r] = gred[mi * 16 + quad * 4 + r];

    // scale + transposed store: St[b][k][n]
    #pragma unroll
    for (int mi = 0; mi < 4; mi++)
        #pragma unroll
        for (int ki = 0; ki < 4; ki++) {
            half4 s4;
            #pragma unroll
            for (int r = 0; r < 4; r++)
                s4[r] = (_Float16)(acc[mi][ki][r] * ginv[mi][r]);
            int k = wk + ki * 16 + l15;
            *(half4*)&St[((size_t)b * KK + k) * NN + n0 + mi * 16 + quad * 4] = s4;
        }
}

// ---------------------------------------------------------------------------
// GEMM2 v7 (unchanged): out[b][k][d] = sum_n St[b][k][n] * Xt[b][d][n]
// 128x128 tile, BK=32, dbuf LDS via lds-dma, XOR swizzle, one __syncthreads
// per K-step; 1-D grid, b-major linearization + bijective XCD swizzle so each
// XCD's L2 holds 4 b's 2.5 MB working set (St reused x6, Xt x4).
// R4 measured the no-reuse cost: 469 MB FETCH, 170 us; with swizzle ~93 us.
// ---------------------------------------------------------------------------
__global__ __launch_bounds__(256, 4) void gemm2_mfma(const _Float16* __restrict__ St,
                                                     const _Float16* __restrict__ Xt,
                                                     float* __restrict__ out) {
    __shared__ _Float16 As[2][128][32];  // 16 KB
    __shared__ _Float16 Bs[2][128][32];  // 16 KB

    // bijective XCD swizzle over 768 blocks (768 % 8 == 0)
    const int lin = blockIdx.x;
    const int wg = (lin & 7) * 96 + (lin >> 3);
    const int b = wg / 24;
    const int rr = wg % 24;
    const int k0 = (rr / 6) * 128;
    const int d0 = (rr % 6) * 128;

    const int t = threadIdx.x;
    const int wave = t >> 6;
    const int lane = t & 63;
    const int wm = (wave >> 1) * 64;
    const int wn = (wave & 1) * 64;
    const int l15 = lane & 15;
    const int quad = lane >> 4;
    const int qs = (quad ^ ((l15 >> 1) & 3)) * 8;

    const int cr = t >> 2;                       // row within 64-row group
    const int cq = (t & 3) ^ ((t >> 3) & 3);     // swizzled source col-chunk

    floatx4 acc[4][4] = {};

    const _Float16* Abase = St + ((size_t)b * KK + k0) * NN;
    const _Float16* Bbase = Xt + ((size_t)b * DD + d0) * NN;

    // prologue: stage chunk 0
    #pragma unroll
    for (int c = 0; c < 2; c++) {
        load_lds16(Abase + (size_t)(c * 64 + cr) * NN + cq * 8,
                   (_Float16*)As[0] + (c * 256 + t) * 8);
        load_lds16(Bbase + (size_t)(c * 64 + cr) * NN + cq * 8,
                   (_Float16*)Bs[0] + (c * 256 + t) * 8);
    }
    __syncthreads();

    int cur = 0;
    for (int it = 0; it < 32; ++it) {
        if (it + 1 < 32) {
            const int n0 = (it + 1) * 32;
            #pragma unroll
            for (int c = 0; c < 2; c++) {
                load_lds16(Abase + (size_t)(c * 64 + cr) * NN + n0 + cq * 8,
                           (_Float16*)As[cur ^ 1] + (c * 256 + t) * 8);
                load_lds16(Bbase + (size_t)(c * 64 + cr) * NN + n0 + cq * 8,
                           (_Float16*)Bs[cur ^ 1] + (c * 256 + t) * 8);
            }
        }
        half8 af[4], bf[4];
        #pragma unroll
        for (int i = 0; i < 4; i++) af[i] = *(half8*)&As[cur][wm + i * 16 + l15][qs];
        #pragma unroll
        for (int i = 0; i < 4; i++) bf[i] = *(half8*)&Bs[cur][wn + i * 16 + l15][qs];
        #pragma unroll
        for (int mi = 0; mi < 4; mi++)
            #pragma unroll
            for (int ni = 0; ni < 4; ni++)
                acc[mi][ni] = __builtin_amdgcn_mfma_f32_16x16x32_f16(af[mi], bf[ni], acc[mi][ni], 0, 0, 0);
        if (it + 1 < 32) { __syncthreads(); cur ^= 1; }
    }

    #pragma unroll
    for (int ni = 0; ni < 4; ni++) {
        #pragma unroll
        for (int mi = 0; mi < 4; mi++) {
            int k = k0 + wm + mi * 16 + quad * 4;
            int d = d0 + wn + ni * 16 + l15;
            float* op = out + ((size_t)b * KK + k) * DD + d;
            floatx4 a = acc[mi][ni];
            op[0 * DD] = a[0];
            op[1 * DD] = a[1];
            op[2 * DD] = a[2];
            op[3 * DD] = a[3];
        }
    }
}

// ---------------------------------------------------------------------------
extern "C" void kernel_launch(void* const* d_in, const int* in_sizes, int n_in,
                              void* d_out, int out_size, void* d_ws, size_t ws_size,
                              hipStream_t stream) {
    const float* x  = (const float*)d_in[0];   // [B,N,D] fp32
    const float* cb = (const float*)d_in[1];   // [K,D] fp32
    float* out = (float*)d_out;                // [B,K,D] fp32

    char* ws = (char*)d_ws;
    float*    csq = (float*)ws;                                   // 4 KB
    _Float16* Cbh = (_Float16*)(ws + 4096);                       // 768 KB
    _Float16* Xt  = (_Float16*)(ws + 4096 + 786432);              // 48 MB [b][d][n]
    _Float16* St  = (_Float16*)(ws + 4096 + 786432 + 50331648);   // 32 MB [b][k][n]

    // codebook prep (merged cast + csq)
    prep_codebook<<<KK, 256, 0, stream>>>(cb, Cbh, csq);

    // fused logits + softmax -> St (fp16 [b][k][n]) AND X transpose -> Xt
    fused_logits_softmax<<<MM / 64, 512, 0, stream>>>(x, Cbh, csq, St, Xt);

    // aggregate (b-major + XCD swizzle)
    gemm2_mfma<<<768, 256, 0, stream>>>(St, Xt, out);
}